// Round 8
// baseline (843.429 us; speedup 1.0000x reference)
//
#include <hip/hip_runtime.h>
#include <stdint.h>

#define T_TOK 1024
#define HID   2048
#define NE    8
#define INTER 5632
#define I2    11264
#define MAXT  24     // worst-case sum ceil(c64/128) over experts
#define RMAX  2560
#define KCH   1408   // INTER/4, GEMM2 K-split chunk

typedef __bf16 bf16x8 __attribute__((ext_vector_type(8)));
typedef float  f32x4  __attribute__((ext_vector_type(4)));
typedef unsigned short u16;

typedef __attribute__((address_space(3))) uint32_t lds_u32;
typedef __attribute__((address_space(1))) uint32_t glb_u32;

// async global->LDS, 16B per lane; LDS dest is the WAVE-UNIFORM base
// (HW adds lane*16); global src is per-lane.
__device__ __forceinline__ void gload16(const void* g, void* l) {
    __builtin_amdgcn_global_load_lds((const glb_u32*)g, (lds_u32*)l, 16, 0, 0);
}

// read 8 f32 from a swizzled LDS row, convert to bf16x8 fragment
__device__ __forceinline__ bf16x8 f32frag(const char* rowbase, int sw, int cb) {
    float4 f0 = *(const float4*)(rowbase + ((cb) ^ sw));
    float4 f1 = *(const float4*)(rowbase + ((cb + 16) ^ sw));
    bf16x8 r;
    r[0] = (__bf16)f0.x; r[1] = (__bf16)f0.y; r[2] = (__bf16)f0.z; r[3] = (__bf16)f0.w;
    r[4] = (__bf16)f1.x; r[5] = (__bf16)f1.y; r[6] = (__bf16)f1.z; r[7] = (__bf16)f1.w;
    return r;
}

#define MFMA __builtin_amdgcn_mfma_f32_16x16x32_bf16
#define SBAR __builtin_amdgcn_s_barrier
#define SCHB __builtin_amdgcn_sched_barrier

// 8 async loads per wave into buffer B; sources pre-offset per lane.
#define STAGE(B, KT)                                                         \
    _Pragma("unroll")                                                        \
    for (int i = 0; i < 8; ++i)                                              \
        gload16(srcp[i] + (KT) * kstepB, smem + dbase + (B) * dstride + i * 1024);

__global__ void moe_router(const float* __restrict__ logits,
                           int* __restrict__ mi, float* __restrict__ mf) {
    int t = blockIdx.x * blockDim.x + threadIdx.x;
    if (t >= T_TOK) return;
    float l[NE];
#pragma unroll
    for (int i = 0; i < NE; ++i) l[i] = logits[t * NE + i];
    int e0 = 0; float v0 = l[0];
#pragma unroll
    for (int i = 1; i < NE; ++i) if (l[i] > v0) { v0 = l[i]; e0 = i; }
    int e1 = -1; float v1 = -3.4e38f;
#pragma unroll
    for (int i = 0; i < NE; ++i) if (i != e0 && l[i] > v1) { v1 = l[i]; e1 = i; }
    float ex = __expf(v1 - v0);
    float s  = 1.f + ex;
    mi[256 + 2 * t]     = e0;
    mi[256 + 2 * t + 1] = e1;
    mf[8192 + 2 * t]     = 1.f / s;
    mf[8192 + 2 * t + 1] = ex / s;
    atomicAdd(&mi[e0], 1);
    atomicAdd(&mi[e1], 1);
}

__global__ void moe_plan(int* __restrict__ mi) {
    int tid = threadIdx.x;
    if (tid == 0) {
        int off = 0, nt = 0;
        for (int e = 0; e < NE; ++e) {
            int c = mi[e];
            mi[24 + e] = off;
            int c64 = ((c + 63) >> 6) << 6;
            int ntile = (c64 + 127) >> 7;
            for (int j = 0; j < ntile; ++j) {
                mi[32 + 2 * nt]     = e;
                mi[32 + 2 * nt + 1] = off + j * 128;
                ++nt;
            }
            off += c64;
            mi[8 + e] = 0;
        }
        mi[16] = nt;
    }
    for (int i = tid; i < RMAX; i += blockDim.x) mi[2560 + i] = -1;
}

__global__ void moe_scatter(int* __restrict__ mi, float* __restrict__ mf) {
    int t = blockIdx.x * blockDim.x + threadIdx.x;
    if (t >= T_TOK) return;
    int e0 = mi[256 + 2 * t], e1 = mi[256 + 2 * t + 1];
    float w0 = mf[8192 + 2 * t], w1 = mf[8192 + 2 * t + 1];
    int p0 = atomicAdd(&mi[8 + e0], 1);
    int s0 = mi[24 + e0] + p0;
    mi[2560 + s0] = t; mf[5632 + s0] = w0;
    int p1 = atomicAdd(&mi[8 + e1], 1);
    int s1 = mi[24 + e1] + p1;
    mi[2560 + s1] = t; mf[5632 + s1] = w1;
}

// ---- GEMM1: 128x(64g+64u), BK=32, gload_lds dbuf + counted vmcnt ----------
// LDS: A bufs [0,32768) (2x16KB), Bg [32768,49152) (2x8KB),
//      Bu [49152,65536) (2x8KB), toks @65536.

#define COMP1(CUR)                                                           \
  { const char* Ab  = smem + (CUR) * 16384;                                  \
    const char* Bgb = smem + 32768 + (CUR) * 8192;                           \
    const char* Bub = smem + 49152 + (CUR) * 8192;                           \
    bf16x8 a0 = f32frag(Ab + (w * 32 + lrow) * 128, sw, lk * 32);            \
    bf16x8 a1 = f32frag(Ab + (w * 32 + 16 + lrow) * 128, sw, lk * 32);       \
    _Pragma("unroll")                                                        \
    for (int fn = 0; fn < 4; ++fn) {                                         \
        bf16x8 bg = f32frag(Bgb + (fn * 16 + lrow) * 128, sw, lk * 32);      \
        bf16x8 bu = f32frag(Bub + (fn * 16 + lrow) * 128, sw, lk * 32);      \
        accg[0][fn] = MFMA(a0, bg, accg[0][fn], 0, 0, 0);                    \
        accg[1][fn] = MFMA(a1, bg, accg[1][fn], 0, 0, 0);                    \
        accu[0][fn] = MFMA(a0, bu, accu[0][fn], 0, 0, 0);                    \
        accu[1][fn] = MFMA(a1, bu, accu[1][fn], 0, 0, 0);                    \
    } }

__global__ __launch_bounds__(256) void moe_gemm1(
        const float* __restrict__ hidden, const float* __restrict__ w13,
        const int* __restrict__ mi, u16* __restrict__ act) {
    const int tj = blockIdx.x, ct = blockIdx.y;   // tj-fastest: same-slice tiles adjacent
    if (tj >= mi[16]) return;
    const int e = mi[32 + 2 * tj], row_base = mi[32 + 2 * tj + 1];
    const int* rowtok = mi + 2560;
    const int limit = mi[24 + e] + (((mi[e] + 63) >> 6) << 6);

    __shared__ __align__(16) char smem[66048];
    int* toks = (int*)(smem + 65536);

    const int tid = threadIdx.x;
    const int w = tid >> 6, lane = tid & 63;
    const int lrow = lane & 15, lk = lane >> 4;
    const int li = lane >> 3, lc = lane & 7;     // staging: row-in-8, 16B chunk
    const int sw = (lrow & 7) << 4;

    if (tid < 128) {
        int idx = row_base + tid;
        toks[tid] = (idx < limit) ? rowtok[idx] : -1;
    }
    __syncthreads();

    // per-wave staging role: w0/w1 -> A rows, w2 -> gate, w3 -> up.
    // source chunk pre-swizzled: LDS chunk c holds global chunk c^(row&7).
    const char* srcp[8];
    const int kstepB = 128;                       // 32 f32 per K-step
    int dbase, dstride;
    if (w < 2) {
        dbase = w * 8192; dstride = 16384;
#pragma unroll
        for (int i = 0; i < 8; ++i) {
            int tok = toks[w * 64 + i * 8 + li];
            if (tok < 0) tok = 0;                 // garbage rows masked at store
            srcp[i] = (const char*)(hidden + (size_t)tok * HID) + ((lc ^ li) << 4);
        }
    } else {
        dbase = (w == 2) ? 32768 : 49152; dstride = 8192;
        const float* wb = w13 + ((size_t)e * I2 + (w == 3 ? INTER : 0)
                                 + (size_t)ct * 64) * HID;
#pragma unroll
        for (int i = 0; i < 8; ++i)
            srcp[i] = (const char*)(wb + (size_t)(i * 8 + li) * HID) + ((lc ^ li) << 4);
    }

    f32x4 accg[2][4] = {}, accu[2][4] = {};

    STAGE(0, 0);
    int cur = 0;
    for (int kt = 0; kt < 63; ++kt) {
        STAGE(cur ^ 1, kt + 1);
        asm volatile("s_waitcnt vmcnt(8)" ::: "memory");
        SCHB(0);
        SBAR();
        SCHB(0);
        COMP1(cur);
        SCHB(0);
        SBAR();
        cur ^= 1;
    }
    asm volatile("s_waitcnt vmcnt(0)" ::: "memory");
    SCHB(0);
    SBAR();
    SCHB(0);
    COMP1(cur);

    // epilogue: silu(g)*u -> act, stored column-swizzled (gemm2 un-swizzles)
    const size_t actbase = (size_t)row_base * INTER + (size_t)ct * 64;
#pragma unroll
    for (int fm = 0; fm < 2; ++fm)
#pragma unroll
    for (int fn = 0; fn < 4; ++fn)
#pragma unroll
    for (int j = 0; j < 4; ++j) {
        int row = w * 32 + fm * 16 + lk * 4 + j;
        int col = fn * 16 + lrow;
        if (toks[row] >= 0) {
            float g = accg[fm][fn][j], u = accu[fm][fn][j];
            float a = g / (1.f + __expf(-g)) * u;
            int colw = col ^ ((row & 7) << 3);
            ((__bf16*)act)[actbase + (size_t)row * INTER + colw] = (__bf16)a;
        }
    }
}

// ---- GEMM2: 128x64 per (tj,ct,kz), BK=64, same pipeline ------------------
// LDS: A bufs [0,32768) (2x16KB bf16, pre-swizzled content, linear gload),
//      B bufs [32768,65536) (2x16KB f32, 256B rows).

#define COMP2(CUR)                                                           \
  { const char* Ab = smem + (CUR) * 16384;                                   \
    const char* Bb = smem + 32768 + (CUR) * 16384;                           \
    _Pragma("unroll")                                                        \
    for (int kk = 0; kk < 2; ++kk) {                                         \
        bf16x8 a0 = *(const bf16x8*)(Ab + (w * 32 + lrow) * 128              \
                                     + ((kk * 64 + lk * 16) ^ sw));          \
        bf16x8 a1 = *(const bf16x8*)(Ab + (w * 32 + 16 + lrow) * 128         \
                                     + ((kk * 64 + lk * 16) ^ sw));          \
        _Pragma("unroll")                                                    \
        for (int fn = 0; fn < 4; ++fn) {                                     \
            bf16x8 b = f32frag(Bb + (fn * 16 + lrow) * 256, sw,              \
                               kk * 128 + lk * 32);                          \
            acc[0][fn] = MFMA(a0, b, acc[0][fn], 0, 0, 0);                   \
            acc[1][fn] = MFMA(a1, b, acc[1][fn], 0, 0, 0);                   \
        }                                                                    \
    } }

__global__ __launch_bounds__(256) void moe_gemm2(
        const u16* __restrict__ act, const float* __restrict__ w2,
        const int* __restrict__ mi, const float* __restrict__ mf,
        float* __restrict__ out) {
    const int tj = blockIdx.x, ct = blockIdx.y, kz = blockIdx.z;
    if (tj >= mi[16]) return;
    const int e = mi[32 + 2 * tj], row_base = mi[32 + 2 * tj + 1];
    const int* rowtok = mi + 2560;
    const float* roww = mf + 5632;
    const int limit = mi[24 + e] + (((mi[e] + 63) >> 6) << 6);

    __shared__ __align__(16) char smem[65536];

    const int tid = threadIdx.x;
    const int w = tid >> 6, lane = tid & 63;
    const int lrow = lane & 15, lk = lane >> 4;
    const int li = lane >> 3, lc = lane & 7;      // 128B-row staging
    const int li2 = lane >> 4, lc2 = lane & 15;   // 256B-row staging
    const int sw = (lrow & 7) << 4;
    const int kbeg = kz * KCH;

    const char* srcp[8];
    int dbase, kstepB;
    const int dstride = 16384;
    if (w < 2) {
        kstepB = 128;                             // 64 bf16 per K-step
        dbase = w * 8192;
#pragma unroll
        for (int i = 0; i < 8; ++i) {
            int slot = row_base + w * 64 + i * 8 + li;
            if (slot > RMAX - 1) slot = RMAX - 1; // garbage rows masked at store
            srcp[i] = (const char*)(act + (size_t)slot * INTER + kbeg) + (lc << 4);
        }
    } else {
        kstepB = 256;                             // 64 f32 per K-step
        dbase = 32768 + (w - 2) * 8192;
        const float* wb = w2 + ((size_t)e * HID + (size_t)ct * 64) * INTER + kbeg;
#pragma unroll
        for (int i = 0; i < 8; ++i) {
            int r = (w - 2) * 32 + i * 4 + li2;
            srcp[i] = (const char*)(wb + (size_t)r * INTER) + ((lc2 ^ (r & 7)) << 4);
        }
    }

    f32x4 acc[2][4] = {};

    STAGE(0, 0);
    int cur = 0;
    for (int kt = 0; kt < 21; ++kt) {
        STAGE(cur ^ 1, kt + 1);
        asm volatile("s_waitcnt vmcnt(8)" ::: "memory");
        SCHB(0);
        SBAR();
        SCHB(0);
        COMP2(cur);
        SCHB(0);
        SBAR();
        cur ^= 1;
    }
    asm volatile("s_waitcnt vmcnt(0)" ::: "memory");
    SCHB(0);
    SBAR();
    SCHB(0);
    COMP2(cur);

#pragma unroll
    for (int fm = 0; fm < 2; ++fm)
#pragma unroll
    for (int fn = 0; fn < 4; ++fn)
#pragma unroll
    for (int j = 0; j < 4; ++j) {
        int row = w * 32 + fm * 16 + lk * 4 + j;
        int col = fn * 16 + lrow;
        int slot = row_base + row;
        if (slot < limit) {
            int tok = rowtok[slot];
            if (tok >= 0)
                atomicAdd(out + (size_t)tok * HID + (size_t)ct * 64 + col,
                          acc[fm][fn][j] * roww[slot]);
        }
    }
}

extern "C" void kernel_launch(void* const* d_in, const int* in_sizes, int n_in,
                              void* d_out, int out_size, void* d_ws, size_t ws_size,
                              hipStream_t stream) {
    const float* hidden = (const float*)d_in[0];
    const float* logits = (const float*)d_in[1];
    const float* w13    = (const float*)d_in[2];
    const float* w2     = (const float*)d_in[3];
    float* out = (float*)d_out;

    int*   mi  = (int*)d_ws;
    float* mf  = (float*)d_ws;
    u16*   act = (u16*)((char*)d_ws + 65536);

    hipMemsetAsync(d_ws, 0, 64, stream);
    hipMemsetAsync(d_out, 0, (size_t)out_size * sizeof(float), stream);

    moe_router<<<dim3(T_TOK / 256), 256, 0, stream>>>(logits, mi, mf);
    moe_plan<<<dim3(1), 256, 0, stream>>>(mi);
    moe_scatter<<<dim3(T_TOK / 256), 256, 0, stream>>>(mi, mf);
    moe_gemm1<<<dim3(MAXT, INTER / 64), 256, 0, stream>>>(hidden, w13, mi, act);
    moe_gemm2<<<dim3(MAXT, HID / 64, INTER / KCH), 256, 0, stream>>>(act, w2, mi, mf, out);
}

// Round 9
// 608.984 us; speedup vs baseline: 1.3850x; 1.3850x over previous
//
#include <hip/hip_runtime.h>
#include <stdint.h>

#define T_TOK 1024
#define HID   2048
#define NE    8
#define INTER 5632
#define I2    11264
#define BK    64
#define MAXT  24     // worst-case sum ceil(c64/128) over experts
#define RMAX  2560
#define KCH   1408   // INTER/4, GEMM2 K-split chunk

typedef __bf16 bf16x8 __attribute__((ext_vector_type(8)));
typedef __bf16 bf16x4 __attribute__((ext_vector_type(4)));
typedef float  f32x4  __attribute__((ext_vector_type(4)));
typedef unsigned short u16;
typedef u16 u16x8 __attribute__((ext_vector_type(8)));

// ws layout: mi/mf meta in [0,64KB); act (bf16, RMAX x INTER) at byte 65536;
// hpk (bf16, T_TOK x HID) at byte 33554432.

__device__ __forceinline__ int swz(int row, int cb) {
    return row * 128 + (cb ^ ((row & 7) << 4));
}

__device__ __forceinline__ bf16x4 cvt4(float4 v) {
    bf16x4 r;
    r[0] = (__bf16)v.x; r[1] = (__bf16)v.y; r[2] = (__bf16)v.z; r[3] = (__bf16)v.w;
    return r;
}

__global__ __launch_bounds__(256) void moe_pack(const float* __restrict__ h,
                                                u16* __restrict__ hpk) {
    int i = blockIdx.x * blockDim.x + threadIdx.x;   // 262144 threads x 8 elems
    float4 a = ((const float4*)h)[2 * i];
    float4 b = ((const float4*)h)[2 * i + 1];
    bf16x8 o;
    o[0] = (__bf16)a.x; o[1] = (__bf16)a.y; o[2] = (__bf16)a.z; o[3] = (__bf16)a.w;
    o[4] = (__bf16)b.x; o[5] = (__bf16)b.y; o[6] = (__bf16)b.z; o[7] = (__bf16)b.w;
    ((bf16x8*)hpk)[i] = o;
}

__global__ void moe_router(const float* __restrict__ logits,
                           int* __restrict__ mi, float* __restrict__ mf) {
    int t = blockIdx.x * blockDim.x + threadIdx.x;
    if (t >= T_TOK) return;
    float l[NE];
#pragma unroll
    for (int i = 0; i < NE; ++i) l[i] = logits[t * NE + i];
    int e0 = 0; float v0 = l[0];
#pragma unroll
    for (int i = 1; i < NE; ++i) if (l[i] > v0) { v0 = l[i]; e0 = i; }
    int e1 = -1; float v1 = -3.4e38f;
#pragma unroll
    for (int i = 0; i < NE; ++i) if (i != e0 && l[i] > v1) { v1 = l[i]; e1 = i; }
    float ex = __expf(v1 - v0);
    float s  = 1.f + ex;
    mi[256 + 2 * t]     = e0;
    mi[256 + 2 * t + 1] = e1;
    mf[8192 + 2 * t]     = 1.f / s;
    mf[8192 + 2 * t + 1] = ex / s;
    atomicAdd(&mi[e0], 1);
    atomicAdd(&mi[e1], 1);
}

__global__ void moe_plan(int* __restrict__ mi) {
    int tid = threadIdx.x;
    if (tid == 0) {
        int off = 0, nt = 0;
        for (int e = 0; e < NE; ++e) {
            int c = mi[e];
            mi[24 + e] = off;
            int c64 = ((c + 63) >> 6) << 6;
            int ntile = (c64 + 127) >> 7;
            for (int j = 0; j < ntile; ++j) {
                mi[32 + 2 * nt]     = e;
                mi[32 + 2 * nt + 1] = off + j * 128;
                ++nt;
            }
            off += c64;
            mi[8 + e] = 0;
        }
        mi[16] = nt;
    }
    for (int i = tid; i < RMAX; i += blockDim.x) mi[2560 + i] = -1;
}

__global__ void moe_scatter(int* __restrict__ mi, float* __restrict__ mf) {
    int t = blockIdx.x * blockDim.x + threadIdx.x;
    if (t >= T_TOK) return;
    int e0 = mi[256 + 2 * t], e1 = mi[256 + 2 * t + 1];
    float w0 = mf[8192 + 2 * t], w1 = mf[8192 + 2 * t + 1];
    int p0 = atomicAdd(&mi[8 + e0], 1);
    int s0 = mi[24 + e0] + p0;
    mi[2560 + s0] = t; mf[5632 + s0] = w0;
    int p1 = atomicAdd(&mi[8 + e1], 1);
    int s1 = mi[24 + e1] + p1;
    mi[2560 + s1] = t; mf[5632 + s1] = w1;
}

// -------- GEMM1: 128x64 tile (gate+up) per block, 2-phase reg pipeline ------
// A sourced from packed bf16 hpk (no cvt); B f32 -> cvt -> bf16 LDS.

#define G1_LOAD(K0)                                                          \
    _Pragma("unroll")                                                        \
    for (int it = 0; it < 4; ++it) {                                         \
        u16x8 z = {};                                                        \
        raa[it] = ap1[it] ? *(const u16x8*)(ap1[it] + (K0)) : z;             \
    }                                                                        \
    _Pragma("unroll")                                                        \
    for (int it = 0; it < 4; ++it) {                                         \
        rg[it] = *(const float4*)(bgp[it] + (K0));                           \
        ru[it] = *(const float4*)(bup[it] + (K0));                           \
    }

#define G1_WRITE()                                                           \
    _Pragma("unroll")                                                        \
    for (int it = 0; it < 4; ++it)                                           \
        *(u16x8*)((char*)As + swz((tid >> 3) + it * 32, acb)) = raa[it];     \
    _Pragma("unroll")                                                        \
    for (int it = 0; it < 4; ++it) {                                         \
        *(bf16x4*)((char*)Bgs + swz(sr + it * 16, scb)) = cvt4(rg[it]);      \
        *(bf16x4*)((char*)Bus + swz(sr + it * 16, scb)) = cvt4(ru[it]);      \
    }

#define G1_MFMA()                                                            \
    _Pragma("unroll")                                                        \
    for (int kk = 0; kk < 2; ++kk) {                                         \
        int kb = kk * 64 + lk * 16;                                          \
        bf16x8 a0 = *(const bf16x8*)((const char*)As + swz(wm * 32 + lrow, kb));      \
        bf16x8 a1 = *(const bf16x8*)((const char*)As + swz(wm * 32 + 16 + lrow, kb)); \
        _Pragma("unroll")                                                    \
        for (int fn = 0; fn < 4; ++fn) {                                     \
            bf16x8 bg = *(const bf16x8*)((const char*)Bgs + swz(fn * 16 + lrow, kb)); \
            bf16x8 bu = *(const bf16x8*)((const char*)Bus + swz(fn * 16 + lrow, kb)); \
            accg[0][fn] = __builtin_amdgcn_mfma_f32_16x16x32_bf16(a0, bg, accg[0][fn], 0, 0, 0); \
            accg[1][fn] = __builtin_amdgcn_mfma_f32_16x16x32_bf16(a1, bg, accg[1][fn], 0, 0, 0); \
            accu[0][fn] = __builtin_amdgcn_mfma_f32_16x16x32_bf16(a0, bu, accu[0][fn], 0, 0, 0); \
            accu[1][fn] = __builtin_amdgcn_mfma_f32_16x16x32_bf16(a1, bu, accu[1][fn], 0, 0, 0); \
        }                                                                    \
    }

__global__ __launch_bounds__(256) void moe_gemm1(
        const u16* __restrict__ hpk, const float* __restrict__ w13,
        const int* __restrict__ mi, u16* __restrict__ act) {
    const int tj = blockIdx.x, ct = blockIdx.y;   // tj-fastest
    if (tj >= mi[16]) return;
    const int e = mi[32 + 2 * tj], row_base = mi[32 + 2 * tj + 1];
    const int* rowtok = mi + 2560;
    const int limit = mi[24 + e] + (((mi[e] + 63) >> 6) << 6);

    __shared__ __align__(16) u16 As[128 * 64];
    __shared__ __align__(16) u16 Bgs[64 * 64];
    __shared__ __align__(16) u16 Bus[64 * 64];
    __shared__ int toks[128];

    const int tid = threadIdx.x;
    const int w = tid >> 6, lane = tid & 63;
    const int wm = w;
    const int lrow = lane & 15, lk = lane >> 4;

    const int sr  = tid >> 4;          // B staging: 0..15
    const int sc  = (tid & 15) * 4;
    const int scb = (tid & 15) * 8;
    const int acb = (tid & 7) * 16;    // A staging byte col

    if (tid < 128) {
        int idx = row_base + tid;
        toks[tid] = (idx < limit) ? rowtok[idx] : -1;
    }
    __syncthreads();

    const u16* ap1[4];
#pragma unroll
    for (int it = 0; it < 4; ++it) {
        int row = (tid >> 3) + it * 32;
        int tok = toks[row];
        ap1[it] = (tok >= 0) ? hpk + (size_t)tok * HID + (tid & 7) * 8 : nullptr;
    }
    const float* bg_base = w13 + ((size_t)e * I2 + (size_t)ct * 64) * HID;
    const float* bu_base = bg_base + (size_t)INTER * HID;
    const float* bgp[4];
    const float* bup[4];
#pragma unroll
    for (int it = 0; it < 4; ++it) {
        bgp[it] = bg_base + (size_t)(sr + it * 16) * HID + sc;
        bup[it] = bu_base + (size_t)(sr + it * 16) * HID + sc;
    }

    f32x4 accg[2][4] = {}, accu[2][4] = {};
    u16x8 raa[4]; float4 rg[4], ru[4];

    G1_LOAD(0)
    G1_WRITE()
    __syncthreads();
    for (int k0 = BK; k0 <= HID; k0 += BK) {
        const bool more = k0 < HID;
        if (more) { G1_LOAD(k0) }
        G1_MFMA()
        __syncthreads();
        if (more) { G1_WRITE() __syncthreads(); }
    }

    const size_t actbase = (size_t)row_base * INTER + (size_t)ct * 64;
#pragma unroll
    for (int fm = 0; fm < 2; ++fm)
#pragma unroll
    for (int fn = 0; fn < 4; ++fn)
#pragma unroll
    for (int j = 0; j < 4; ++j) {
        int row = wm * 32 + fm * 16 + lk * 4 + j;
        int col = fn * 16 + lrow;
        if (toks[row] >= 0) {
            float g = accg[fm][fn][j], u = accu[fm][fn][j];
            float a = g / (1.f + __expf(-g)) * u;
            ((__bf16*)act)[actbase + (size_t)row * INTER + col] = (__bf16)a;
        }
    }
}

// -------- GEMM2: 128x64 tile per (tile, ct, kz) block; K-split z=4 ----------

#define G2_LOAD(K0)                                                          \
    _Pragma("unroll")                                                        \
    for (int it = 0; it < 4; ++it)                                           \
        raa[it] = *(const u16x8*)(ap2[it] + (K0));                           \
    _Pragma("unroll")                                                        \
    for (int it = 0; it < 4; ++it)                                           \
        rb[it] = *(const float4*)(bp2[it] + (K0));

#define G2_WRITE()                                                           \
    _Pragma("unroll")                                                        \
    for (int it = 0; it < 4; ++it)                                           \
        *(u16x8*)((char*)As2 + swz((tid >> 3) + it * 32, acb)) = raa[it];    \
    _Pragma("unroll")                                                        \
    for (int it = 0; it < 4; ++it)                                           \
        *(bf16x4*)((char*)Bs2 + swz(sr + it * 16, scb)) = cvt4(rb[it]);

#define G2_MFMA()                                                            \
    _Pragma("unroll")                                                        \
    for (int kk = 0; kk < 2; ++kk) {                                         \
        int kb = kk * 64 + lk * 16;                                          \
        bf16x8 a0 = *(const bf16x8*)((const char*)As2 + swz(wm * 32 + lrow, kb));      \
        bf16x8 a1 = *(const bf16x8*)((const char*)As2 + swz(wm * 32 + 16 + lrow, kb)); \
        _Pragma("unroll")                                                    \
        for (int fn = 0; fn < 4; ++fn) {                                     \
            bf16x8 b = *(const bf16x8*)((const char*)Bs2 + swz(fn * 16 + lrow, kb)); \
            acc[0][fn] = __builtin_amdgcn_mfma_f32_16x16x32_bf16(a0, b, acc[0][fn], 0, 0, 0); \
            acc[1][fn] = __builtin_amdgcn_mfma_f32_16x16x32_bf16(a1, b, acc[1][fn], 0, 0, 0); \
        }                                                                    \
    }

__global__ __launch_bounds__(256) void moe_gemm2(
        const u16* __restrict__ act, const float* __restrict__ w2,
        const int* __restrict__ mi, const float* __restrict__ mf,
        float* __restrict__ out) {
    const int tj = blockIdx.x, ct = blockIdx.y, kz = blockIdx.z;  // ct 0..31
    if (tj >= mi[16]) return;
    const int e = mi[32 + 2 * tj], row_base = mi[32 + 2 * tj + 1];
    const int* rowtok = mi + 2560;
    const float* roww = mf + 5632;
    const int limit = mi[24 + e] + (((mi[e] + 63) >> 6) << 6);

    __shared__ __align__(16) u16 As2[128 * 64];
    __shared__ __align__(16) u16 Bs2[64 * 64];

    const int tid = threadIdx.x;
    const int w = tid >> 6, lane = tid & 63;
    const int wm = w;
    const int lrow = lane & 15, lk = lane >> 4;

    const int sr  = tid >> 4;
    const int sc  = (tid & 15) * 4;
    const int scb = (tid & 15) * 8;
    const int ac  = (tid & 7) * 8;
    const int acb = (tid & 7) * 16;

    const u16* ap2[4];
#pragma unroll
    for (int it = 0; it < 4; ++it) {
        int r = row_base + (tid >> 3) + it * 32;
        if (r > RMAX - 1) r = RMAX - 1;            // clamp: garbage rows discarded per-row
        ap2[it] = act + (size_t)r * INTER + ac;
    }
    const float* b_base = w2 + ((size_t)e * HID + (size_t)ct * 64) * INTER;
    const float* bp2[4];
#pragma unroll
    for (int it = 0; it < 4; ++it)
        bp2[it] = b_base + (size_t)(sr + it * 16) * INTER + sc;

    const int kbeg = kz * KCH, kend = kbeg + KCH;

    f32x4 acc[2][4] = {};
    u16x8 raa[4]; float4 rb[4];

    G2_LOAD(kbeg)
    G2_WRITE()
    __syncthreads();
    for (int k0 = kbeg + BK; k0 <= kend; k0 += BK) {
        const bool more = k0 < kend;
        if (more) { G2_LOAD(k0) }
        G2_MFMA()
        __syncthreads();
        if (more) { G2_WRITE() __syncthreads(); }
    }

#pragma unroll
    for (int fm = 0; fm < 2; ++fm)
#pragma unroll
    for (int fn = 0; fn < 4; ++fn)
#pragma unroll
    for (int j = 0; j < 4; ++j) {
        int row = wm * 32 + fm * 16 + lk * 4 + j;
        int col = fn * 16 + lrow;
        int slot = row_base + row;
        if (slot < limit) {
            int tok = rowtok[slot];
            if (tok >= 0)
                atomicAdd(out + (size_t)tok * HID + (size_t)ct * 64 + col,
                          acc[fm][fn][j] * roww[slot]);
        }
    }
}

extern "C" void kernel_launch(void* const* d_in, const int* in_sizes, int n_in,
                              void* d_out, int out_size, void* d_ws, size_t ws_size,
                              hipStream_t stream) {
    const float* hidden = (const float*)d_in[0];
    const float* logits = (const float*)d_in[1];
    const float* w13    = (const float*)d_in[2];
    const float* w2     = (const float*)d_in[3];
    float* out = (float*)d_out;

    int*   mi  = (int*)d_ws;
    float* mf  = (float*)d_ws;
    u16*   act = (u16*)((char*)d_ws + 65536);
    u16*   hpk = (u16*)((char*)d_ws + 33554432);

    hipMemsetAsync(d_ws, 0, 64, stream);
    hipMemsetAsync(d_out, 0, (size_t)out_size * sizeof(float), stream);

    moe_pack<<<dim3(T_TOK * HID / 8 / 256), 256, 0, stream>>>(hidden, hpk);
    moe_router<<<dim3(T_TOK / 256), 256, 0, stream>>>(logits, mi, mf);
    moe_plan<<<dim3(1), 256, 0, stream>>>(mi);
    moe_scatter<<<dim3(T_TOK / 256), 256, 0, stream>>>(mi, mf);
    moe_gemm1<<<dim3(MAXT, INTER / 64), 256, 0, stream>>>(hpk, w13, mi, act);
    moe_gemm2<<<dim3(MAXT, HID / 64, INTER / KCH), 256, 0, stream>>>(act, w2, mi, mf, out);
}

// Round 10
// 538.107 us; speedup vs baseline: 1.5674x; 1.1317x over previous
//
#include <hip/hip_runtime.h>
#include <stdint.h>

#define T_TOK 1024
#define HID   2048
#define NE    8
#define INTER 5632
#define I2    11264
#define BK    64
#define MAXT  18     // worst-case sum ceil(c64/256) over experts (<=17)
#define RMAX  2560
#define KCH   1408   // INTER/4, GEMM2 K-split chunk

typedef __bf16 bf16x8 __attribute__((ext_vector_type(8)));
typedef __bf16 bf16x4 __attribute__((ext_vector_type(4)));
typedef float  f32x4  __attribute__((ext_vector_type(4)));
typedef unsigned short u16;
typedef u16 u16x8 __attribute__((ext_vector_type(8)));

// ws layout: mi/mf meta in [0,64KB); act (bf16, RMAX x INTER) at byte 65536;
// hpk (bf16, T_TOK x HID) at byte 33554432.

__device__ __forceinline__ int swz(int row, int cb) {
    return row * 128 + (cb ^ ((row & 7) << 4));
}

__device__ __forceinline__ bf16x4 cvt4(float4 v) {
    bf16x4 r;
    r[0] = (__bf16)v.x; r[1] = (__bf16)v.y; r[2] = (__bf16)v.z; r[3] = (__bf16)v.w;
    return r;
}

__global__ __launch_bounds__(256) void moe_pack(const float* __restrict__ h,
                                                u16* __restrict__ hpk) {
    int i = blockIdx.x * blockDim.x + threadIdx.x;
    float4 a = ((const float4*)h)[2 * i];
    float4 b = ((const float4*)h)[2 * i + 1];
    bf16x8 o;
    o[0] = (__bf16)a.x; o[1] = (__bf16)a.y; o[2] = (__bf16)a.z; o[3] = (__bf16)a.w;
    o[4] = (__bf16)b.x; o[5] = (__bf16)b.y; o[6] = (__bf16)b.z; o[7] = (__bf16)b.w;
    ((bf16x8*)hpk)[i] = o;
}

__global__ void moe_router(const float* __restrict__ logits,
                           int* __restrict__ mi, float* __restrict__ mf) {
    int t = blockIdx.x * blockDim.x + threadIdx.x;
    if (t >= T_TOK) return;
    float l[NE];
#pragma unroll
    for (int i = 0; i < NE; ++i) l[i] = logits[t * NE + i];
    int e0 = 0; float v0 = l[0];
#pragma unroll
    for (int i = 1; i < NE; ++i) if (l[i] > v0) { v0 = l[i]; e0 = i; }
    int e1 = -1; float v1 = -3.4e38f;
#pragma unroll
    for (int i = 0; i < NE; ++i) if (i != e0 && l[i] > v1) { v1 = l[i]; e1 = i; }
    float ex = __expf(v1 - v0);
    float s  = 1.f + ex;
    mi[256 + 2 * t]     = e0;
    mi[256 + 2 * t + 1] = e1;
    mf[8192 + 2 * t]     = 1.f / s;
    mf[8192 + 2 * t + 1] = ex / s;
    atomicAdd(&mi[e0], 1);
    atomicAdd(&mi[e1], 1);
}

__global__ void moe_plan(int* __restrict__ mi) {
    int tid = threadIdx.x;
    if (tid == 0) {
        int off = 0, nt = 0;
        for (int e = 0; e < NE; ++e) {
            int c = mi[e];
            mi[24 + e] = off;
            int c64 = ((c + 63) >> 6) << 6;          // 64-padded slot region
            int ntile = (c64 + 255) >> 8;            // 256-row tiles
            for (int j = 0; j < ntile; ++j) {
                mi[32 + 2 * nt]     = e;
                mi[32 + 2 * nt + 1] = off + j * 256;
                ++nt;
            }
            off += c64;
            mi[8 + e] = 0;
        }
        mi[16] = nt;
    }
    for (int i = tid; i < RMAX; i += blockDim.x) mi[2560 + i] = -1;
}

__global__ void moe_scatter(int* __restrict__ mi, float* __restrict__ mf) {
    int t = blockIdx.x * blockDim.x + threadIdx.x;
    if (t >= T_TOK) return;
    int e0 = mi[256 + 2 * t], e1 = mi[256 + 2 * t + 1];
    float w0 = mf[8192 + 2 * t], w1 = mf[8192 + 2 * t + 1];
    int p0 = atomicAdd(&mi[8 + e0], 1);
    int s0 = mi[24 + e0] + p0;
    mi[2560 + s0] = t; mf[5632 + s0] = w0;
    int p1 = atomicAdd(&mi[8 + e1], 1);
    int s1 = mi[24 + e1] + p1;
    mi[2560 + s1] = t; mf[5632 + s1] = w1;
}

// ---- GEMM1: 256x(64g+64u) tile per block, 512 threads, 2-phase pipeline ----
// merged LDS: As @0 (32KB bf16), Bg @32768 (8KB), Bu @40960 (8KB), toks @49152

#define G1_LOAD(K0)                                                          \
    _Pragma("unroll")                                                        \
    for (int it = 0; it < 4; ++it) {                                         \
        u16x8 z = {};                                                        \
        raa[it] = ap1[it] ? *(const u16x8*)(ap1[it] + (K0)) : z;             \
    }                                                                        \
    _Pragma("unroll")                                                        \
    for (int it = 0; it < 2; ++it) {                                         \
        rg[it] = *(const float4*)(bgp[it] + (K0));                           \
        ru[it] = *(const float4*)(bup[it] + (K0));                           \
    }

#define G1_WRITE()                                                           \
    _Pragma("unroll")                                                        \
    for (int it = 0; it < 4; ++it)                                           \
        *(u16x8*)(As + swz((tid >> 3) + it * 64, acb)) = raa[it];            \
    _Pragma("unroll")                                                        \
    for (int it = 0; it < 2; ++it) {                                         \
        *(bf16x4*)(Bgs + swz(sr + it * 32, scb)) = cvt4(rg[it]);             \
        *(bf16x4*)(Bus + swz(sr + it * 32, scb)) = cvt4(ru[it]);             \
    }

#define G1_MFMA()                                                            \
    _Pragma("unroll")                                                        \
    for (int kk = 0; kk < 2; ++kk) {                                         \
        int kb = kk * 64 + lk * 16;                                          \
        bf16x8 a0 = *(const bf16x8*)(As + swz(w * 32 + lrow, kb));           \
        bf16x8 a1 = *(const bf16x8*)(As + swz(w * 32 + 16 + lrow, kb));      \
        _Pragma("unroll")                                                    \
        for (int fn = 0; fn < 4; ++fn) {                                     \
            bf16x8 bg = *(const bf16x8*)(Bgs + swz(fn * 16 + lrow, kb));     \
            bf16x8 bu = *(const bf16x8*)(Bus + swz(fn * 16 + lrow, kb));     \
            accg[0][fn] = __builtin_amdgcn_mfma_f32_16x16x32_bf16(a0, bg, accg[0][fn], 0, 0, 0); \
            accg[1][fn] = __builtin_amdgcn_mfma_f32_16x16x32_bf16(a1, bg, accg[1][fn], 0, 0, 0); \
            accu[0][fn] = __builtin_amdgcn_mfma_f32_16x16x32_bf16(a0, bu, accu[0][fn], 0, 0, 0); \
            accu[1][fn] = __builtin_amdgcn_mfma_f32_16x16x32_bf16(a1, bu, accu[1][fn], 0, 0, 0); \
        }                                                                    \
    }

__global__ __launch_bounds__(512) void moe_gemm1(
        const u16* __restrict__ hpk, const float* __restrict__ w13,
        const int* __restrict__ mi, u16* __restrict__ act) {
    const int tj = blockIdx.x, ct = blockIdx.y;   // tj-fastest
    if (tj >= mi[16]) return;
    const int e = mi[32 + 2 * tj], row_base = mi[32 + 2 * tj + 1];
    const int* rowtok = mi + 2560;
    const int limit = mi[24 + e] + (((mi[e] + 63) >> 6) << 6);

    __shared__ __align__(16) char smem[50176];
    char* As  = smem;
    char* Bgs = smem + 32768;
    char* Bus = smem + 40960;
    int*  toks = (int*)(smem + 49152);

    const int tid = threadIdx.x;
    const int w = tid >> 6, lane = tid & 63;
    const int lrow = lane & 15, lk = lane >> 4;

    const int sr  = tid >> 4;          // B staging: 0..31
    const int sc  = (tid & 15) * 4;
    const int scb = (tid & 15) * 8;
    const int acb = (tid & 7) * 16;    // A staging byte col

    if (tid < 256) {
        int idx = row_base + tid;
        toks[tid] = (idx < limit) ? rowtok[idx] : -1;
    }
    __syncthreads();

    const u16* ap1[4];
#pragma unroll
    for (int it = 0; it < 4; ++it) {
        int tok = toks[(tid >> 3) + it * 64];
        ap1[it] = (tok >= 0) ? hpk + (size_t)tok * HID + (tid & 7) * 8 : nullptr;
    }
    const float* bg_base = w13 + ((size_t)e * I2 + (size_t)ct * 64) * HID;
    const float* bu_base = bg_base + (size_t)INTER * HID;
    const float* bgp[2];
    const float* bup[2];
#pragma unroll
    for (int it = 0; it < 2; ++it) {
        bgp[it] = bg_base + (size_t)(sr + it * 32) * HID + sc;
        bup[it] = bu_base + (size_t)(sr + it * 32) * HID + sc;
    }

    f32x4 accg[2][4] = {}, accu[2][4] = {};
    u16x8 raa[4]; float4 rg[2], ru[2];

    G1_LOAD(0)
    G1_WRITE()
    __syncthreads();
    for (int k0 = BK; k0 <= HID; k0 += BK) {
        const bool more = k0 < HID;
        if (more) { G1_LOAD(k0) }
        G1_MFMA()
        __syncthreads();
        if (more) { G1_WRITE() __syncthreads(); }
    }

    const size_t actbase = (size_t)row_base * INTER + (size_t)ct * 64;
#pragma unroll
    for (int fm = 0; fm < 2; ++fm)
#pragma unroll
    for (int fn = 0; fn < 4; ++fn)
#pragma unroll
    for (int j = 0; j < 4; ++j) {
        int row = w * 32 + fm * 16 + lk * 4 + j;
        int col = fn * 16 + lrow;
        if (toks[row] >= 0) {
            float g = accg[fm][fn][j], u = accu[fm][fn][j];
            float a = g / (1.f + __expf(-g)) * u;
            ((__bf16*)act)[actbase + (size_t)row * INTER + col] = (__bf16)a;
        }
    }
}

// ---- GEMM2: 256x64 tile per (tj, ct, kz) block, 512 threads, K-split z=4 ---
// merged LDS: As2 @0 (32KB bf16), Bs2 @32768 (8KB)

#define G2_LOAD(K0)                                                          \
    _Pragma("unroll")                                                        \
    for (int it = 0; it < 4; ++it) {                                         \
        u16x8 z = {};                                                        \
        raa[it] = ap2[it] ? *(const u16x8*)(ap2[it] + (K0)) : z;             \
    }                                                                        \
    _Pragma("unroll")                                                        \
    for (int it = 0; it < 2; ++it)                                           \
        rb[it] = *(const float4*)(bp2[it] + (K0));

#define G2_WRITE()                                                           \
    _Pragma("unroll")                                                        \
    for (int it = 0; it < 4; ++it)                                           \
        *(u16x8*)(As2 + swz((tid >> 3) + it * 64, acb)) = raa[it];           \
    _Pragma("unroll")                                                        \
    for (int it = 0; it < 2; ++it)                                           \
        *(bf16x4*)(Bs2 + swz(sr + it * 32, scb)) = cvt4(rb[it]);

#define G2_MFMA()                                                            \
    _Pragma("unroll")                                                        \
    for (int kk = 0; kk < 2; ++kk) {                                         \
        int kb = kk * 64 + lk * 16;                                          \
        bf16x8 a0 = *(const bf16x8*)(As2 + swz(w * 32 + lrow, kb));          \
        bf16x8 a1 = *(const bf16x8*)(As2 + swz(w * 32 + 16 + lrow, kb));     \
        _Pragma("unroll")                                                    \
        for (int fn = 0; fn < 4; ++fn) {                                     \
            bf16x8 b = *(const bf16x8*)(Bs2 + swz(fn * 16 + lrow, kb));      \
            acc[0][fn] = __builtin_amdgcn_mfma_f32_16x16x32_bf16(a0, b, acc[0][fn], 0, 0, 0); \
            acc[1][fn] = __builtin_amdgcn_mfma_f32_16x16x32_bf16(a1, b, acc[1][fn], 0, 0, 0); \
        }                                                                    \
    }

__global__ __launch_bounds__(512) void moe_gemm2(
        const u16* __restrict__ act, const float* __restrict__ w2,
        const int* __restrict__ mi, const float* __restrict__ mf,
        float* __restrict__ out) {
    const int tj = blockIdx.x, ct = blockIdx.y, kz = blockIdx.z;  // ct 0..31
    if (tj >= mi[16]) return;
    const int e = mi[32 + 2 * tj], row_base = mi[32 + 2 * tj + 1];
    const int* rowtok = mi + 2560;
    const float* roww = mf + 5632;
    const int limit = mi[24 + e] + (((mi[e] + 63) >> 6) << 6);

    __shared__ __align__(16) char smem[40960];
    char* As2 = smem;
    char* Bs2 = smem + 32768;

    const int tid = threadIdx.x;
    const int w = tid >> 6, lane = tid & 63;
    const int lrow = lane & 15, lk = lane >> 4;

    const int sr  = tid >> 4;
    const int sc  = (tid & 15) * 4;
    const int scb = (tid & 15) * 8;
    const int ac  = (tid & 7) * 8;
    const int acb = (tid & 7) * 16;
    const int kbeg = kz * KCH, kend = kbeg + KCH;

    const u16* ap2[4];
#pragma unroll
    for (int it = 0; it < 4; ++it) {
        int slot = row_base + (tid >> 3) + it * 64;
        bool ok = (slot < limit) && (rowtok[slot] >= 0);
        ap2[it] = ok ? act + (size_t)slot * INTER + ac : nullptr;
    }
    const float* b_base = w2 + ((size_t)e * HID + (size_t)ct * 64) * INTER;
    const float* bp2[2];
#pragma unroll
    for (int it = 0; it < 2; ++it)
        bp2[it] = b_base + (size_t)(sr + it * 32) * INTER + sc;

    f32x4 acc[2][4] = {};
    u16x8 raa[4]; float4 rb[2];

    G2_LOAD(kbeg)
    G2_WRITE()
    __syncthreads();
    for (int k0 = kbeg + BK; k0 <= kend; k0 += BK) {
        const bool more = k0 < kend;
        if (more) { G2_LOAD(k0) }
        G2_MFMA()
        __syncthreads();
        if (more) { G2_WRITE() __syncthreads(); }
    }

#pragma unroll
    for (int fm = 0; fm < 2; ++fm)
#pragma unroll
    for (int fn = 0; fn < 4; ++fn)
#pragma unroll
    for (int j = 0; j < 4; ++j) {
        int row = w * 32 + fm * 16 + lk * 4 + j;
        int col = fn * 16 + lrow;
        int slot = row_base + row;
        if (slot < limit) {
            int tok = rowtok[slot];
            if (tok >= 0)
                atomicAdd(out + (size_t)tok * HID + (size_t)ct * 64 + col,
                          acc[fm][fn][j] * roww[slot]);
        }
    }
}

extern "C" void kernel_launch(void* const* d_in, const int* in_sizes, int n_in,
                              void* d_out, int out_size, void* d_ws, size_t ws_size,
                              hipStream_t stream) {
    const float* hidden = (const float*)d_in[0];
    const float* logits = (const float*)d_in[1];
    const float* w13    = (const float*)d_in[2];
    const float* w2     = (const float*)d_in[3];
    float* out = (float*)d_out;

    int*   mi  = (int*)d_ws;
    float* mf  = (float*)d_ws;
    u16*   act = (u16*)((char*)d_ws + 65536);
    u16*   hpk = (u16*)((char*)d_ws + 33554432);

    hipMemsetAsync(d_ws, 0, 64, stream);
    hipMemsetAsync(d_out, 0, (size_t)out_size * sizeof(float), stream);

    moe_pack<<<dim3(T_TOK * HID / 8 / 256), 256, 0, stream>>>(hidden, hpk);
    moe_router<<<dim3(T_TOK / 256), 256, 0, stream>>>(logits, mi, mf);
    moe_plan<<<dim3(1), 256, 0, stream>>>(mi);
    moe_scatter<<<dim3(T_TOK / 256), 256, 0, stream>>>(mi, mf);
    moe_gemm1<<<dim3(MAXT, INTER / 64), 512, 0, stream>>>(hpk, w13, mi, act);
    moe_gemm2<<<dim3(MAXT, HID / 64, INTER / KCH), 512, 0, stream>>>(act, w2, mi, mf, out);
}